// Round 6
// baseline (301.908 us; speedup 1.0000x reference)
//
#include <hip/hip_runtime.h>

// ---- problem constants (fixed by reference setup_inputs) ----
constexpr int B_  = 32;
constexpr int Na  = 512;
constexpr int Nv  = 256;
constexpr int D   = 384;

constexpr int BK  = 32;        // k-chunk per iteration
constexpr int BN  = 128;       // audio rows per block (one n-chunk)
constexpr int NK  = D / BK;    // 12 k-iters
constexpr int NCH = Na / BN;   // 4 n-chunks -> grid = 32*32*4

typedef short  bf16x8  __attribute__((ext_vector_type(8)));
typedef float  floatx4 __attribute__((ext_vector_type(4)));
typedef unsigned short ushort8v __attribute__((ext_vector_type(8)));

// fp32 -> bf16 round-to-nearest-even
__device__ __forceinline__ unsigned short f2bf(float f) {
    unsigned int u = __float_as_uint(f);
    u += 0x7fffu + ((u >> 16) & 1u);
    return (unsigned short)(u >> 16);
}

// 16B-per-lane async global->LDS (lane i writes LDS slot base + i*16)
__device__ __forceinline__ void async_load16(const void* g, void* l) {
    __builtin_amdgcn_global_load_lds(
        (const __attribute__((address_space(1))) unsigned int*)g,
        (__attribute__((address_space(3))) unsigned int*)l,
        16, 0, 0);
}

// ---- K1: zero output + one-shot fp32 -> bf16 conversion into workspace ----
__global__ void convert_kernel(const float* __restrict__ a, const float* __restrict__ v,
                               unsigned short* __restrict__ abf, unsigned short* __restrict__ vbf,
                               float* __restrict__ out) {
    constexpr int NA8 = B_ * Na * D / 8;   // 786,432 float8 groups
    constexpr int NV8 = B_ * Nv * D / 8;   // 393,216
    int gid = blockIdx.x * blockDim.x + threadIdx.x;
    if (gid < B_ * B_) out[gid] = 0.0f;    // d_out is poisoned before every launch
    int stride = gridDim.x * blockDim.x;
    for (int i = gid; i < NA8 + NV8; i += stride) {
        const float4* src;
        unsigned short* dst;
        int j;
        if (i < NA8) { src = (const float4*)a; dst = abf; j = i; }
        else         { src = (const float4*)v; dst = vbf; j = i - NA8; }
        float4 f0 = src[2 * j];
        float4 f1 = src[2 * j + 1];
        ushort8v o = { f2bf(f0.x), f2bf(f0.y), f2bf(f0.z), f2bf(f0.w),
                       f2bf(f1.x), f2bf(f1.y), f2bf(f1.z), f2bf(f1.w) };
        *(ushort8v*)&dst[j * 8] = o;
    }
}

// ---- K2: fused bf16 GEMM + logsumexp-pool ----
// Wave tile 64 rows x 128 cols (col-split): wave w -> rows (w>>1)*64..+63,
// cols (w&1)*128..+127. Each B-fragment ds_read feeds 4 MFMAs (vs 2 in the
// 32x256 tile), halving LDS traffic; MFMA pipe becomes the pole.
// A: 4 fragments straight from global into regs, distance-1 prefetch.
// B: double-buffered LDS via global_load_lds, ONE barrier per k-iter.
// Register budget: acc 4x8 floatx4 = 128 + A cur/next 32 + addr ~70 = ~230;
// __launch_bounds__(256,2) -> 256/wave cap, no spill (round-3/4/5 lesson).
__global__ __launch_bounds__(256, 2) void gemm_lse_kernel(
        const unsigned short* __restrict__ abf,
        const unsigned short* __restrict__ vbf,
        float* __restrict__ out)
{
    __shared__ unsigned short blds[2][Nv * BK];   // 2 x 16 KB
    __shared__ float ms[2][64][2][2];             // [rowhalf][row][colhalf][{max,sum}] 2 KB
    __shared__ float wsum[2];

    // hierarchical decode: any 512-consecutive-bid window = 8 bi x 16 bj x 4 nc
    // -> working set 8*393KB (A) + 16*196KB (B) = 6.3 MB (vs 13+ MB naive)
    int t = blockIdx.x;
    const int nc    = t & 3;          t >>= 2;
    const int bj_lo = t & 15;         t >>= 4;
    const int bi_lo = t & 7;          t >>= 3;
    const int bj_hi = t & 1;          t >>= 1;
    const int bi    = t * 8 + bi_lo;
    const int bj    = bj_hi * 16 + bj_lo;

    const int tid  = threadIdx.x;
    const int lane = tid & 63;
    const int wave = tid >> 6;
    const int fr   = lane & 15;    // free index within a 16-tile / staging row-in-group
    const int g    = lane >> 4;    // k-quarter / staging chunk index
    const int rh   = wave >> 1;    // row half (0: rows 0-63, 1: rows 64-127)
    const int ch   = wave & 1;     // col half (0: cols 0-127, 1: cols 128-255)

    const unsigned short* Ab = abf + ((size_t)bi * Na + nc * BN) * D;
    const unsigned short* Bb = vbf + (size_t)bj * Nv * D;

    // B staging source pointers (each wave stages a quarter of the 16 KB chunk)
    const unsigned short* bg[4];
    #pragma unroll
    for (int q = 0; q < 4; ++q)
        bg[q] = Bb + (size_t)((wave * 4 + q) * 16 + fr) * D + g * 8;

    // A fragment global addresses: 4 x 16-row fragments covering rows rh*64..+63
    const unsigned short* aptr[4];
    #pragma unroll
    for (int af = 0; af < 4; ++af)
        aptr[af] = Ab + (size_t)(rh * 64 + af * 16 + fr) * D + g * 8;

    // ---- prologue: issue B[0], load A[0] ----
    #pragma unroll
    for (int q = 0; q < 4; ++q)
        async_load16(bg[q], (void*)&blds[0][(wave * 4 + q) * 512]);
    bf16x8 a[4], na[4];
    #pragma unroll
    for (int af = 0; af < 4; ++af) a[af] = *(const bf16x8*)aptr[af];

    floatx4 acc[4][8];
    #pragma unroll
    for (int af = 0; af < 4; ++af)
        #pragma unroll
        for (int mt = 0; mt < 8; ++mt)
            acc[af][mt] = (floatx4){0.f, 0.f, 0.f, 0.f};

    #pragma unroll
    for (int k = 0; k < NK; ++k) {
        // drains vmcnt(0): waits on B[k]/A-prefetches issued one compute-phase ago
        __syncthreads();

        #pragma unroll
        for (int af = 0; af < 4; ++af) na[af] = a[af];
        if (k + 1 < NK) {
            #pragma unroll
            for (int q = 0; q < 4; ++q)
                async_load16(bg[q] + (k + 1) * BK,
                             (void*)&blds[(k + 1) & 1][(wave * 4 + q) * 512]);
            #pragma unroll
            for (int af = 0; af < 4; ++af)
                na[af] = *(const bf16x8*)(aptr[af] + (k + 1) * BK);
        }

        const unsigned short* buf = blds[k & 1];
        #pragma unroll
        for (int mt = 0; mt < 8; ++mt) {
            bf16x8 bfr = *(const bf16x8*)&buf[(ch * 8 + mt) * 512 + g * 128 + fr * 8];
            #pragma unroll
            for (int af = 0; af < 4; ++af)
                acc[af][mt] = __builtin_amdgcn_mfma_f32_16x16x32_bf16(a[af], bfr, acc[af][mt], 0, 0, 0);
        }
        #pragma unroll
        for (int af = 0; af < 4; ++af) a[af] = na[af];
    }

    // ---- epilogue: per-row partial (max, sumexp) over this wave's 128 cols ----
    // C/D layout: col = ch*128 + mt*16 + (lane&15), row = af*16 + (lane>>4)*4 + reg
    constexpr float INV_TAU_LN2 = 0.7213475204444817f;  // 1/(tau*ln2), tau=2
    constexpr float TAU_LN2     = 1.3862943611198906f;  // tau*ln2
    const int q4 = (lane >> 4) * 4;

    #pragma unroll
    for (int af = 0; af < 4; ++af) {
        #pragma unroll
        for (int r = 0; r < 4; ++r) {
            float vmax = acc[af][0][r];
            #pragma unroll
            for (int mt = 1; mt < 8; ++mt) vmax = fmaxf(vmax, acc[af][mt][r]);
            #pragma unroll
            for (int m = 1; m < 16; m <<= 1)
                vmax = fmaxf(vmax, __shfl_xor(vmax, m, 64));
            float s2 = 0.f;
            #pragma unroll
            for (int mt = 0; mt < 8; ++mt)
                s2 += exp2f((acc[af][mt][r] - vmax) * INV_TAU_LN2);
            #pragma unroll
            for (int m = 1; m < 16; m <<= 1)
                s2 += __shfl_xor(s2, m, 64);
            if (fr == 0) {
                int row = af * 16 + q4 + r;
                ms[rh][row][ch][0] = vmax;
                ms[rh][row][ch][1] = s2;
            }
        }
    }
    __syncthreads();

    // merge col-halves, logsumexp, and block-sum (threads 0..127, one row each)
    if (tid < 128) {
        const int rh2 = tid >> 6, row = tid & 63;
        float m0 = ms[rh2][row][0][0], s0 = ms[rh2][row][0][1];
        float m1 = ms[rh2][row][1][0], s1 = ms[rh2][row][1][1];
        float mm = fmaxf(m0, m1);
        float ss = s0 * exp2f((m0 - mm) * INV_TAU_LN2)
                 + s1 * exp2f((m1 - mm) * INV_TAU_LN2);
        float lse = mm + TAU_LN2 * log2f(ss);
        #pragma unroll
        for (int d = 1; d < 64; d <<= 1) lse += __shfl_xor(lse, d, 64);
        if ((tid & 63) == 0) wsum[tid >> 6] = lse;
    }
    __syncthreads();
    if (tid == 0)
        atomicAdd(&out[bi * 32 + bj], (wsum[0] + wsum[1]) * (1.0f / Na));
}

extern "C" void kernel_launch(void* const* d_in, const int* in_sizes, int n_in,
                              void* d_out, int out_size, void* d_ws, size_t ws_size,
                              hipStream_t stream) {
    const float* audio  = (const float*)d_in[0];
    const float* visual = (const float*)d_in[1];
    float* out = (float*)d_out;

    unsigned short* abf = (unsigned short*)d_ws;                 // 12.58 MB
    unsigned short* vbf = abf + (size_t)B_ * Na * D;             // +6.29 MB

    convert_kernel<<<dim3(2048), dim3(256), 0, stream>>>(audio, visual, abf, vbf, out);
    gemm_lse_kernel<<<dim3(B_ * B_ * NCH), dim3(256), 0, stream>>>(abf, vbf, out);
}

// Round 7
// 221.550 us; speedup vs baseline: 1.3627x; 1.3627x over previous
//
#include <hip/hip_runtime.h>

// ---- problem constants (fixed by reference setup_inputs) ----
constexpr int B_  = 32;
constexpr int Na  = 512;
constexpr int Nv  = 256;
constexpr int D   = 384;

constexpr int BK  = 32;        // k-chunk per iteration
constexpr int BN  = 128;       // audio rows per block (one n-chunk)
constexpr int NK  = D / BK;    // 12 k-iters
constexpr int NCH = Na / BN;   // 4 n-chunks -> grid = 32*32*4

// swizzled-unit counts (one unit = 64 lanes x 16 B = 1 KB staged per instruction)
constexpr int AUNITS = B_ * NCH * 2 * 4 * NK * 64;  // 786,432 (12.58 MB)
constexpr int BUNITS = B_ * NK * 16 * 64;           // 393,216 (6.29 MB)

typedef short  bf16x8  __attribute__((ext_vector_type(8)));
typedef float  floatx4 __attribute__((ext_vector_type(4)));
typedef unsigned short ushort8v __attribute__((ext_vector_type(8)));

// fp32 -> bf16 round-to-nearest-even
__device__ __forceinline__ unsigned short f2bf(float f) {
    unsigned int u = __float_as_uint(f);
    u += 0x7fffu + ((u >> 16) & 1u);
    return (unsigned short)(u >> 16);
}

// 16B-per-lane async global->LDS (lane i writes LDS slot base + i*16)
__device__ __forceinline__ void async_load16(const void* g, void* l) {
    __builtin_amdgcn_global_load_lds(
        (const __attribute__((address_space(1))) unsigned int*)g,
        (__attribute__((address_space(3))) unsigned int*)l,
        16, 0, 0);
}

// ---- K1: zero output + fp32 -> bf16 conversion into FRAGMENT-SWIZZLED layout ----
// asw unit u = ((((bi*4+nc)*2+rh)*4+af)*12+k)*64 + l  holds
//   A[bi][nc*128+rh*64+af*16+(l&15)][k*32+(l>>4)*8 .. +8)
// bsw unit u = ((bj*12+k)*16+wq)*64 + l  holds
//   V[bj][wq*16+(l&15)][k*32+(l>>4)*8 .. +8)
// => every gemm staging instruction reads a CONTIGUOUS 1 KB block (lane-linear),
//    fixing the 16-way row-scatter that round-5/6 staging paid per VMEM op.
__global__ void convert_swizzle_kernel(const float* __restrict__ a, const float* __restrict__ v,
                                       unsigned short* __restrict__ asw,
                                       unsigned short* __restrict__ bsw,
                                       float* __restrict__ out) {
    int gid = blockIdx.x * blockDim.x + threadIdx.x;
    if (gid < B_ * B_) out[gid] = 0.0f;    // d_out is poisoned before every launch
    int stride = gridDim.x * blockDim.x;
    for (int u = gid; u < AUNITS + BUNITS; u += stride) {
        const float* srcp;
        unsigned short* dst;
        if (u < AUNITS) {
            int l = u & 63;
            int t = u >> 6;
            int k  = t % 12;  t /= 12;
            int af = t & 3;   t >>= 2;
            int rh = t & 1;   t >>= 1;
            int nc = t & 3;   t >>= 2;
            int bi = t;
            int row = bi * Na + nc * BN + rh * 64 + af * 16 + (l & 15);
            int kel = k * BK + (l >> 4) * 8;
            srcp = a + (size_t)row * D + kel;
            dst  = asw + (size_t)u * 8;
        } else {
            int u2 = u - AUNITS;
            int l = u2 & 63;
            int t = u2 >> 6;
            int wq = t & 15;  t >>= 4;
            int k  = t % 12;
            int bj = t / 12;
            int row = bj * Nv + wq * 16 + (l & 15);
            int kel = k * BK + (l >> 4) * 8;
            srcp = v + (size_t)row * D + kel;
            dst  = bsw + (size_t)u2 * 8;
        }
        float4 f0 = ((const float4*)srcp)[0];
        float4 f1 = ((const float4*)srcp)[1];
        ushort8v o = { f2bf(f0.x), f2bf(f0.y), f2bf(f0.z), f2bf(f0.w),
                       f2bf(f1.x), f2bf(f1.y), f2bf(f1.z), f2bf(f1.w) };
        *(ushort8v*)dst = o;   // output-linear: perfectly coalesced 16B/lane
    }
}

// ---- K2: fused bf16 GEMM + logsumexp-pool ----
// Wave tile 64 rows x 128 cols; A in registers (distance-1 prefetch), B double-
// buffered LDS via global_load_lds, ONE barrier per k-iter. All staging loads
// are lane-linear contiguous 1 KB (pre-swizzled operands). Register budget:
// acc 128 + A 64 + addr -> __launch_bounds__(256,2) (256/wave cap, no spill).
__global__ __launch_bounds__(256, 2) void gemm_lse_kernel(
        const unsigned short* __restrict__ asw,
        const unsigned short* __restrict__ bsw,
        float* __restrict__ out)
{
    __shared__ unsigned short blds[2][Nv * BK];   // 2 x 16 KB
    __shared__ float ms[2][64][2][2];             // [rowhalf][row][colhalf][{max,sum}]
    __shared__ float wsum[2];

    // hierarchical decode: any 512-consecutive-bid window = 8 bi x 16 bj x 4 nc
    int t = blockIdx.x;
    const int nc    = t & 3;          t >>= 2;
    const int bj_lo = t & 15;         t >>= 4;
    const int bi_lo = t & 7;          t >>= 3;
    const int bj_hi = t & 1;          t >>= 1;
    const int bi    = t * 8 + bi_lo;
    const int bj    = bj_hi * 16 + bj_lo;

    const int tid  = threadIdx.x;
    const int lane = tid & 63;
    const int wave = tid >> 6;
    const int fr   = lane & 15;
    const int g    = lane >> 4;
    const int rh   = wave >> 1;    // row half (0: rows 0-63, 1: rows 64-127)
    const int ch   = wave & 1;     // col half (0: cols 0-127, 1: cols 128-255)

    // A fragment sources: contiguous 1 KB per (af,k); lane offset = lane*8 shorts
    const unsigned short* aptr[4];
    #pragma unroll
    for (int af = 0; af < 4; ++af)
        aptr[af] = asw + ((size_t)((((bi * 4 + nc) * 2 + rh) * 4 + af) * 12) * 64 + lane) * 8;

    // B staging sources: contiguous 1 KB per (wq,k)
    const unsigned short* bg[4];
    #pragma unroll
    for (int q = 0; q < 4; ++q)
        bg[q] = bsw + ((size_t)(((bj * 12) * 16) + wave * 4 + q) * 64 + lane) * 8;

    // ---- prologue: issue B[0], load A[0] ----
    #pragma unroll
    for (int q = 0; q < 4; ++q)
        async_load16(bg[q], (void*)&blds[0][(wave * 4 + q) * 512]);
    bf16x8 a[4], na[4];
    #pragma unroll
    for (int af = 0; af < 4; ++af) a[af] = *(const bf16x8*)aptr[af];

    floatx4 acc[4][8];
    #pragma unroll
    for (int af = 0; af < 4; ++af)
        #pragma unroll
        for (int mt = 0; mt < 8; ++mt)
            acc[af][mt] = (floatx4){0.f, 0.f, 0.f, 0.f};

    #pragma unroll
    for (int k = 0; k < NK; ++k) {
        __syncthreads();   // drains loads issued one full compute-phase ago

        #pragma unroll
        for (int af = 0; af < 4; ++af) na[af] = a[af];
        if (k + 1 < NK) {
            #pragma unroll
            for (int q = 0; q < 4; ++q)
                async_load16(bg[q] + (size_t)(k + 1) * 16 * 512,      // +16 KB per k
                             (void*)&blds[(k + 1) & 1][(wave * 4 + q) * 512]);
            #pragma unroll
            for (int af = 0; af < 4; ++af)
                na[af] = *(const bf16x8*)(aptr[af] + (size_t)(k + 1) * 512);  // +1 KB per k
        }

        const unsigned short* buf = blds[k & 1];
        #pragma unroll
        for (int mt = 0; mt < 8; ++mt) {
            bf16x8 bfr = *(const bf16x8*)&buf[(ch * 8 + mt) * 512 + g * 128 + fr * 8];
            #pragma unroll
            for (int af = 0; af < 4; ++af)
                acc[af][mt] = __builtin_amdgcn_mfma_f32_16x16x32_bf16(a[af], bfr, acc[af][mt], 0, 0, 0);
        }
        #pragma unroll
        for (int af = 0; af < 4; ++af) a[af] = na[af];
    }

    // ---- epilogue: per-row partial (max, sumexp) over this wave's 128 cols ----
    // C/D layout: col = ch*128 + mt*16 + (lane&15), row = af*16 + (lane>>4)*4 + reg
    constexpr float INV_TAU_LN2 = 0.7213475204444817f;  // 1/(tau*ln2), tau=2
    constexpr float TAU_LN2     = 1.3862943611198906f;  // tau*ln2
    const int q4 = (lane >> 4) * 4;

    #pragma unroll
    for (int af = 0; af < 4; ++af) {
        #pragma unroll
        for (int r = 0; r < 4; ++r) {
            float vmax = acc[af][0][r];
            #pragma unroll
            for (int mt = 1; mt < 8; ++mt) vmax = fmaxf(vmax, acc[af][mt][r]);
            #pragma unroll
            for (int m = 1; m < 16; m <<= 1)
                vmax = fmaxf(vmax, __shfl_xor(vmax, m, 64));
            float s2 = 0.f;
            #pragma unroll
            for (int mt = 0; mt < 8; ++mt)
                s2 += exp2f((acc[af][mt][r] - vmax) * INV_TAU_LN2);
            #pragma unroll
            for (int m = 1; m < 16; m <<= 1)
                s2 += __shfl_xor(s2, m, 64);
            if (fr == 0) {
                int row = af * 16 + q4 + r;
                ms[rh][row][ch][0] = vmax;
                ms[rh][row][ch][1] = s2;
            }
        }
    }
    __syncthreads();

    // merge col-halves, logsumexp, and block-sum (threads 0..127, one row each)
    if (tid < 128) {
        const int rh2 = tid >> 6, row = tid & 63;
        float m0 = ms[rh2][row][0][0], s0 = ms[rh2][row][0][1];
        float m1 = ms[rh2][row][1][0], s1 = ms[rh2][row][1][1];
        float mm = fmaxf(m0, m1);
        float ss = s0 * exp2f((m0 - mm) * INV_TAU_LN2)
                 + s1 * exp2f((m1 - mm) * INV_TAU_LN2);
        float lse = mm + TAU_LN2 * log2f(ss);
        #pragma unroll
        for (int d = 1; d < 64; d <<= 1) lse += __shfl_xor(lse, d, 64);
        if ((tid & 63) == 0) wsum[tid >> 6] = lse;
    }
    __syncthreads();
    if (tid == 0)
        atomicAdd(&out[bi * 32 + bj], (wsum[0] + wsum[1]) * (1.0f / Na));
}

extern "C" void kernel_launch(void* const* d_in, const int* in_sizes, int n_in,
                              void* d_out, int out_size, void* d_ws, size_t ws_size,
                              hipStream_t stream) {
    const float* audio  = (const float*)d_in[0];
    const float* visual = (const float*)d_in[1];
    float* out = (float*)d_out;

    unsigned short* asw = (unsigned short*)d_ws;                 // 12.58 MB swizzled A
    unsigned short* bsw = asw + (size_t)AUNITS * 8;              // +6.29 MB swizzled B

    convert_swizzle_kernel<<<dim3(1024), dim3(256), 0, stream>>>(audio, visual, asw, bsw, out);
    gemm_lse_kernel<<<dim3(B_ * B_ * NCH), dim3(256), 0, stream>>>(asw, bsw, out);
}

// Round 8
// 213.619 us; speedup vs baseline: 1.4133x; 1.0371x over previous
//
#include <hip/hip_runtime.h>

// ---- problem constants (fixed by reference setup_inputs) ----
constexpr int B_  = 32;
constexpr int Na  = 512;
constexpr int Nv  = 256;
constexpr int D   = 384;

constexpr int BK  = 32;        // k-chunk per iteration
constexpr int BN  = 128;       // audio rows per block (one n-chunk)
constexpr int NK  = D / BK;    // 12 k-iters
constexpr int NCH = Na / BN;   // 4 n-chunks -> grid = 32*32*4

// swizzled-unit counts (one unit = 64 lanes x 16 B = 1 KB staged per instruction)
constexpr int AUNITS = B_ * NCH * 2 * 4 * NK * 64;  // 786,432 (12.58 MB)
constexpr int BUNITS = B_ * NK * 16 * 64;           // 393,216 (6.29 MB)

typedef short  bf16x8  __attribute__((ext_vector_type(8)));
typedef float  floatx4 __attribute__((ext_vector_type(4)));
typedef unsigned short ushort8v __attribute__((ext_vector_type(8)));

// fp32 -> bf16 round-to-nearest-even
__device__ __forceinline__ unsigned short f2bf(float f) {
    unsigned int u = __float_as_uint(f);
    u += 0x7fffu + ((u >> 16) & 1u);
    return (unsigned short)(u >> 16);
}

// 16B-per-lane async global->LDS (lane i writes LDS slot base + i*16)
__device__ __forceinline__ void async_load16(const void* g, void* l) {
    __builtin_amdgcn_global_load_lds(
        (const __attribute__((address_space(1))) unsigned int*)g,
        (__attribute__((address_space(3))) unsigned int*)l,
        16, 0, 0);
}

// ---- K1: zero output + fp32 -> bf16 conversion into FRAGMENT-SWIZZLED layout ----
// asw unit u = ((((bi*4+nc)*2+rh)*4+af)*12+k)*64 + l  holds
//   A[bi][nc*128+rh*64+af*16+(l&15)][k*32+(l>>4)*8 .. +8)
// bsw unit u = ((bj*12+k)*16+wq)*64 + l  holds
//   V[bj][wq*16+(l&15)][k*32+(l>>4)*8 .. +8)
// => every gemm staging instruction reads a CONTIGUOUS 1 KB block (lane-linear).
__global__ void convert_swizzle_kernel(const float* __restrict__ a, const float* __restrict__ v,
                                       unsigned short* __restrict__ asw,
                                       unsigned short* __restrict__ bsw,
                                       float* __restrict__ out) {
    int gid = blockIdx.x * blockDim.x + threadIdx.x;
    if (gid < B_ * B_) out[gid] = 0.0f;    // d_out is poisoned before every launch
    int stride = gridDim.x * blockDim.x;
    for (int u = gid; u < AUNITS + BUNITS; u += stride) {
        const float* srcp;
        unsigned short* dst;
        if (u < AUNITS) {
            int l = u & 63;
            int t = u >> 6;
            int k  = t % 12;  t /= 12;
            int af = t & 3;   t >>= 2;
            int rh = t & 1;   t >>= 1;
            int nc = t & 3;   t >>= 2;
            int bi = t;
            int row = bi * Na + nc * BN + rh * 64 + af * 16 + (l & 15);
            int kel = k * BK + (l >> 4) * 8;
            srcp = a + (size_t)row * D + kel;
            dst  = asw + (size_t)u * 8;
        } else {
            int u2 = u - AUNITS;
            int l = u2 & 63;
            int t = u2 >> 6;
            int wq = t & 15;  t >>= 4;
            int k  = t % 12;
            int bj = t / 12;
            int row = bj * Nv + wq * 16 + (l & 15);
            int kel = k * BK + (l >> 4) * 8;
            srcp = v + (size_t)row * D + kel;
            dst  = bsw + (size_t)u2 * 8;
        }
        float4 f0 = ((const float4*)srcp)[0];
        float4 f1 = ((const float4*)srcp)[1];
        ushort8v o = { f2bf(f0.x), f2bf(f0.y), f2bf(f0.z), f2bf(f0.w),
                       f2bf(f1.x), f2bf(f1.y), f2bf(f1.z), f2bf(f1.w) };
        *(ushort8v*)dst = o;   // output-linear: perfectly coalesced 16B/lane
    }
}

// ---- K2: fused bf16 GEMM + logsumexp-pool, depth-2 software pipeline ----
// Triple-buffered LDS ring for A and B. Iter k: issue batch k+2 (6 VMEM/wave),
// s_waitcnt vmcnt(12) (only batch k must have retired; k+1/k+2 stay in flight
// ACROSS the barrier), raw s_barrier, compute k. This gives every load ~2
// compute-phases to land (covers HBM-class misses) — the structure __syncthreads
// cannot express (it drains vmcnt(0), capping prefetch at depth 1).
// Ring-3 safety: slot (k+2)%3 written in iter k was last read in iter k-1,
// and all waves passed barrier k after finishing iter k-1's reads.
__global__ __launch_bounds__(256, 2) void gemm_lse_kernel(
        const unsigned short* __restrict__ asw,
        const unsigned short* __restrict__ bsw,
        float* __restrict__ out)
{
    __shared__ unsigned short blds[3][Nv * BK];   // 3 x 16 KB
    __shared__ unsigned short alds[3][BN * BK];   // 3 x  8 KB
    __shared__ float ms[2][64][2][2];             // [rowhalf][row][colhalf][{max,sum}]
    __shared__ float wsum[2];

    // hierarchical decode: any 512-consecutive-bid window = 8 bi x 16 bj x 4 nc
    int t = blockIdx.x;
    const int nc    = t & 3;          t >>= 2;
    const int bj_lo = t & 15;         t >>= 4;
    const int bi_lo = t & 7;          t >>= 3;
    const int bj_hi = t & 1;          t >>= 1;
    const int bi    = t * 8 + bi_lo;
    const int bj    = bj_hi * 16 + bj_lo;

    const int tid  = threadIdx.x;
    const int lane = tid & 63;
    const int wave = tid >> 6;
    const int fr   = lane & 15;
    const int g    = lane >> 4;
    const int rh   = wave >> 1;    // row half (0: rows 0-63, 1: rows 64-127)
    const int ch   = wave & 1;     // col half (0: cols 0-127, 1: cols 128-255)

    // B staging sources: wave stages units wq = wave*4+q (4 x 1 KB per k)
    const unsigned short* bg[4];
    #pragma unroll
    for (int q = 0; q < 4; ++q)
        bg[q] = bsw + ((size_t)(((bj * 12) * 16) + wave * 4 + q) * 64 + lane) * 8;

    // A staging sources: wave stages units u = wave and wave+4 (2 x 1 KB per k)
    // asw unit index for (bi,nc,u,k) = ((bi*4+nc)*8 + u)*12 + k
    const unsigned short* ag[2];
    #pragma unroll
    for (int q = 0; q < 2; ++q)
        ag[q] = asw + ((size_t)(((bi * 4 + nc) * 8 + wave + q * 4) * 12) * 64 + lane) * 8;

    // issue one batch (6 global_load_lds per wave) for k-chunk kk into ring slot
    auto issue_batch = [&](int kk) {
        int slot = kk % 3;
        #pragma unroll
        for (int q = 0; q < 4; ++q)
            async_load16(bg[q] + (size_t)kk * 16 * 512,
                         (void*)&blds[slot][(wave * 4 + q) * 512]);
        #pragma unroll
        for (int q = 0; q < 2; ++q)
            async_load16(ag[q] + (size_t)kk * 512,
                         (void*)&alds[slot][(wave + q * 4) * 512]);
    };

    // ---- prologue: batches 0 and 1 in flight ----
    issue_batch(0);
    issue_batch(1);

    floatx4 acc[4][8];
    #pragma unroll
    for (int af = 0; af < 4; ++af)
        #pragma unroll
        for (int mt = 0; mt < 8; ++mt)
            acc[af][mt] = (floatx4){0.f, 0.f, 0.f, 0.f};

    #pragma unroll
    for (int k = 0; k < NK; ++k) {
        if (k + 2 < NK) issue_batch(k + 2);

        // wait for THIS wave's batch k to retire (vmcnt FIFO: <=12 outstanding
        // means only batches k+1,k+2 remain), then cross-wave raw barrier.
        asm volatile("" ::: "memory");
        if (k + 2 < NK)      __builtin_amdgcn_s_waitcnt(0xF7C);  // vmcnt(12)
        else if (k + 1 < NK) __builtin_amdgcn_s_waitcnt(0xF76);  // vmcnt(6)
        else                 __builtin_amdgcn_s_waitcnt(0xF70);  // vmcnt(0)
        __builtin_amdgcn_s_barrier();
        asm volatile("" ::: "memory");

        const int slot = k % 3;
        const unsigned short* abuf = alds[slot];
        const unsigned short* bbuf = blds[slot];

        bf16x8 a[4];
        #pragma unroll
        for (int af = 0; af < 4; ++af)
            a[af] = *(const bf16x8*)&abuf[(rh * 4 + af) * 512 + g * 128 + fr * 8];

        #pragma unroll
        for (int mt = 0; mt < 8; ++mt) {
            bf16x8 bfr = *(const bf16x8*)&bbuf[(ch * 8 + mt) * 512 + g * 128 + fr * 8];
            #pragma unroll
            for (int af = 0; af < 4; ++af)
                acc[af][mt] = __builtin_amdgcn_mfma_f32_16x16x32_bf16(a[af], bfr, acc[af][mt], 0, 0, 0);
        }
    }

    // ---- epilogue: per-row partial (max, sumexp) over this wave's 128 cols ----
    // C/D layout: col = ch*128 + mt*16 + (lane&15), row = af*16 + (lane>>4)*4 + reg
    constexpr float INV_TAU_LN2 = 0.7213475204444817f;  // 1/(tau*ln2), tau=2
    constexpr float TAU_LN2     = 1.3862943611198906f;  // tau*ln2
    const int q4 = (lane >> 4) * 4;

    #pragma unroll
    for (int af = 0; af < 4; ++af) {
        #pragma unroll
        for (int r = 0; r < 4; ++r) {
            float vmax = acc[af][0][r];
            #pragma unroll
            for (int mt = 1; mt < 8; ++mt) vmax = fmaxf(vmax, acc[af][mt][r]);
            #pragma unroll
            for (int m = 1; m < 16; m <<= 1)
                vmax = fmaxf(vmax, __shfl_xor(vmax, m, 64));
            float s2 = 0.f;
            #pragma unroll
            for (int mt = 0; mt < 8; ++mt)
                s2 += exp2f((acc[af][mt][r] - vmax) * INV_TAU_LN2);
            #pragma unroll
            for (int m = 1; m < 16; m <<= 1)
                s2 += __shfl_xor(s2, m, 64);
            if (fr == 0) {
                int row = af * 16 + q4 + r;
                ms[rh][row][ch][0] = vmax;
                ms[rh][row][ch][1] = s2;
            }
        }
    }
    __syncthreads();

    // merge col-halves, logsumexp, and block-sum (threads 0..127, one row each)
    if (tid < 128) {
        const int rh2 = tid >> 6, row = tid & 63;
        float m0 = ms[rh2][row][0][0], s0 = ms[rh2][row][0][1];
        float m1 = ms[rh2][row][1][0], s1 = ms[rh2][row][1][1];
        float mm = fmaxf(m0, m1);
        float ss = s0 * exp2f((m0 - mm) * INV_TAU_LN2)
                 + s1 * exp2f((m1 - mm) * INV_TAU_LN2);
        float lse = mm + TAU_LN2 * log2f(ss);
        #pragma unroll
        for (int d = 1; d < 64; d <<= 1) lse += __shfl_xor(lse, d, 64);
        if ((tid & 63) == 0) wsum[tid >> 6] = lse;
    }
    __syncthreads();
    if (tid == 0)
        atomicAdd(&out[bi * 32 + bj], (wsum[0] + wsum[1]) * (1.0f / Na));
}

extern "C" void kernel_launch(void* const* d_in, const int* in_sizes, int n_in,
                              void* d_out, int out_size, void* d_ws, size_t ws_size,
                              hipStream_t stream) {
    const float* audio  = (const float*)d_in[0];
    const float* visual = (const float*)d_in[1];
    float* out = (float*)d_out;

    unsigned short* asw = (unsigned short*)d_ws;                 // 12.58 MB swizzled A
    unsigned short* bsw = asw + (size_t)AUNITS * 8;              // +6.29 MB swizzled B

    convert_swizzle_kernel<<<dim3(1024), dim3(256), 0, stream>>>(audio, visual, asw, bsw, out);
    gemm_lse_kernel<<<dim3(B_ * B_ * NCH), dim3(256), 0, stream>>>(asw, bsw, out);
}

// Round 9
// 208.911 us; speedup vs baseline: 1.4452x; 1.0225x over previous
//
#include <hip/hip_runtime.h>

// ---- problem constants (fixed by reference setup_inputs) ----
constexpr int B_  = 32;
constexpr int Na  = 512;
constexpr int Nv  = 256;
constexpr int D   = 384;

constexpr int BK  = 32;        // k-chunk per iteration
constexpr int BN  = 64;        // audio rows per block (one n-chunk)
constexpr int NK  = D / BK;    // 12 k-iters
constexpr int NCH = Na / BN;   // 8 n-chunks -> grid = 32*32*8

// swizzled units: 1 unit = 64 lanes x 16 B = 1 KB, lane-linear
constexpr int AUNITS = B_ * NCH * 4 * NK * 64;      // 786,432 (12.58 MB)
constexpr int BUNITS = B_ * NK * 16 * 64;           // 393,216 (6.29 MB)

typedef short  bf16x8  __attribute__((ext_vector_type(8)));
typedef float  floatx4 __attribute__((ext_vector_type(4)));
typedef unsigned short ushort8v __attribute__((ext_vector_type(8)));

// fp32 -> bf16 round-to-nearest-even
__device__ __forceinline__ unsigned short f2bf(float f) {
    unsigned int u = __float_as_uint(f);
    u += 0x7fffu + ((u >> 16) & 1u);
    return (unsigned short)(u >> 16);
}

// 16B-per-lane async global->LDS (lane i writes LDS slot base + i*16)
__device__ __forceinline__ void async_load16(const void* g, void* l) {
    __builtin_amdgcn_global_load_lds(
        (const __attribute__((address_space(1))) unsigned int*)g,
        (__attribute__((address_space(3))) unsigned int*)l,
        16, 0, 0);
}

// ---- K1: zero output + fp32 -> bf16 conversion into FRAGMENT-SWIZZLED layout ----
// A unit u = ((bi*8+nc8)*4+uq)*12+k  (lane l) holds
//   A[bi][nc8*64+uq*16+(l&15)][k*32+(l>>4)*8 .. +8)
// B unit u = (bj*12+k)*16+wq  (lane l) holds
//   V[bj][wq*16+(l&15)][k*32+(l>>4)*8 .. +8)
// => every gemm staging instruction reads a CONTIGUOUS 1 KB block (lane-linear).
__global__ void convert_swizzle_kernel(const float* __restrict__ a, const float* __restrict__ v,
                                       unsigned short* __restrict__ asw,
                                       unsigned short* __restrict__ bsw,
                                       float* __restrict__ out) {
    int gid = blockIdx.x * blockDim.x + threadIdx.x;
    if (gid < B_ * B_) out[gid] = 0.0f;    // d_out is poisoned before every launch
    int stride = gridDim.x * blockDim.x;
    for (int u = gid; u < AUNITS + BUNITS; u += stride) {
        const float* srcp;
        unsigned short* dst;
        if (u < AUNITS) {
            int l = u & 63;
            int t = u >> 6;
            int k   = t % 12;  t /= 12;
            int uq  = t & 3;   t >>= 2;
            int nc8 = t & 7;   t >>= 3;
            int bi  = t;
            int row = bi * Na + nc8 * BN + uq * 16 + (l & 15);
            int kel = k * BK + (l >> 4) * 8;
            srcp = a + (size_t)row * D + kel;
            dst  = asw + (size_t)u * 8;
        } else {
            int u2 = u - AUNITS;
            int l = u2 & 63;
            int t = u2 >> 6;
            int wq = t & 15;  t >>= 4;
            int k  = t % 12;
            int bj = t / 12;
            int row = bj * Nv + wq * 16 + (l & 15);
            int kel = k * BK + (l >> 4) * 8;
            srcp = v + (size_t)row * D + kel;
            dst  = bsw + (size_t)u2 * 8;
        }
        float4 f0 = ((const float4*)srcp)[0];
        float4 f1 = ((const float4*)srcp)[1];
        ushort8v o = { f2bf(f0.x), f2bf(f0.y), f2bf(f0.z), f2bf(f0.w),
                       f2bf(f1.x), f2bf(f1.y), f2bf(f1.z), f2bf(f1.w) };
        *(ushort8v*)dst = o;   // output-linear: perfectly coalesced 16B/lane
    }
}

// ---- K2: fused bf16 GEMM + logsumexp-pool, occupancy-first variant ----
// Block-tile 64 rows x 256 cols; wave-tile 32x128 -> acc = 64 regs/wave.
// With ~55 arch VGPRs that fits the 128-reg cap of __launch_bounds__(256,4):
// 4 blocks/CU = 16 waves/CU = 4 waves/SIMD (2x round-8 TLP — the measured
// MfmaUtil-per-wave ratio says utilization scales with waves/SIMD).
// B: ring-2 LDS via global_load_lds, depth-1 prefetch, __syncthreads per iter
// (round-7 proven; round-8's raw-barrier ring-3 had a race and gained nothing).
// A: straight from swizzled global into regs, distance-1 prefetch.
__global__ __launch_bounds__(256, 4) void gemm_lse_kernel(
        const unsigned short* __restrict__ asw,
        const unsigned short* __restrict__ bsw,
        float* __restrict__ out)
{
    __shared__ unsigned short blds[2][Nv * BK];   // 2 x 16 KB
    __shared__ float ms[BN][2][2];                // [row][colhalf][{max,sum}] 1 KB

    // hierarchical decode: any 1024-consecutive-bid window = 8 bi x 16 bj x 8 nc
    int t = blockIdx.x;
    const int nc8   = t & 7;          t >>= 3;
    const int bj_lo = t & 15;         t >>= 4;
    const int bi_lo = t & 7;          t >>= 3;
    const int bj_hi = t & 1;          t >>= 1;
    const int bi    = t * 8 + bi_lo;
    const int bj    = bj_hi * 16 + bj_lo;

    const int tid  = threadIdx.x;
    const int lane = tid & 63;
    const int wave = tid >> 6;
    const int fr   = lane & 15;
    const int g    = lane >> 4;
    const int rh   = wave >> 1;    // row half (0: rows 0-31, 1: rows 32-63)
    const int ch   = wave & 1;     // col half (0: cols 0-127, 1: cols 128-255)

    // A fragment sources: frag af (rows rh*32+af*16) = unit (bi*8+nc8)*4 + rh*2+af
    const unsigned short* aptr[2];
    #pragma unroll
    for (int af = 0; af < 2; ++af)
        aptr[af] = asw + ((size_t)(((bi * 8 + nc8) * 4 + rh * 2 + af) * 12) * 64 + lane) * 8;

    // B staging sources: wave stages units wq = wave*4+q (4 x 1 KB per k)
    const unsigned short* bg[4];
    #pragma unroll
    for (int q = 0; q < 4; ++q)
        bg[q] = bsw + ((size_t)((bj * 12) * 16 + wave * 4 + q) * 64 + lane) * 8;

    // ---- prologue: issue B[0], load A[0] ----
    #pragma unroll
    for (int q = 0; q < 4; ++q)
        async_load16(bg[q], (void*)&blds[0][(wave * 4 + q) * 512]);
    bf16x8 a[2], na[2];
    #pragma unroll
    for (int af = 0; af < 2; ++af) a[af] = *(const bf16x8*)aptr[af];

    floatx4 acc[2][8];
    #pragma unroll
    for (int af = 0; af < 2; ++af)
        #pragma unroll
        for (int mt = 0; mt < 8; ++mt)
            acc[af][mt] = (floatx4){0.f, 0.f, 0.f, 0.f};

    #pragma unroll
    for (int k = 0; k < NK; ++k) {
        __syncthreads();   // drains loads issued one full compute-phase ago

        #pragma unroll
        for (int af = 0; af < 2; ++af) na[af] = a[af];
        if (k + 1 < NK) {
            #pragma unroll
            for (int q = 0; q < 4; ++q)
                async_load16(bg[q] + (size_t)(k + 1) * 16 * 512,      // +16 KB per k
                             (void*)&blds[(k + 1) & 1][(wave * 4 + q) * 512]);
            #pragma unroll
            for (int af = 0; af < 2; ++af)
                na[af] = *(const bf16x8*)(aptr[af] + (size_t)(k + 1) * 512);  // +1 KB per k
        }

        const unsigned short* buf = blds[k & 1];
        #pragma unroll
        for (int mt = 0; mt < 8; ++mt) {
            bf16x8 bfr = *(const bf16x8*)&buf[(ch * 8 + mt) * 512 + g * 128 + fr * 8];
            #pragma unroll
            for (int af = 0; af < 2; ++af)
                acc[af][mt] = __builtin_amdgcn_mfma_f32_16x16x32_bf16(a[af], bfr, acc[af][mt], 0, 0, 0);
        }
        #pragma unroll
        for (int af = 0; af < 2; ++af) a[af] = na[af];
    }

    // ---- epilogue: per-row partial (max, sumexp) over this wave's 128 cols ----
    // C/D layout: col = ch*128 + mt*16 + (lane&15), row = rh*32 + af*16 + (lane>>4)*4 + reg
    constexpr float INV_TAU_LN2 = 0.7213475204444817f;  // 1/(tau*ln2), tau=2
    constexpr float TAU_LN2     = 1.3862943611198906f;  // tau*ln2
    const int q4 = (lane >> 4) * 4;

    #pragma unroll
    for (int af = 0; af < 2; ++af) {
        #pragma unroll
        for (int r = 0; r < 4; ++r) {
            float vmax = acc[af][0][r];
            #pragma unroll
            for (int mt = 1; mt < 8; ++mt) vmax = fmaxf(vmax, acc[af][mt][r]);
            #pragma unroll
            for (int m = 1; m < 16; m <<= 1)
                vmax = fmaxf(vmax, __shfl_xor(vmax, m, 64));
            float s2 = 0.f;
            #pragma unroll
            for (int mt = 0; mt < 8; ++mt)
                s2 += exp2f((acc[af][mt][r] - vmax) * INV_TAU_LN2);
            #pragma unroll
            for (int m = 1; m < 16; m <<= 1)
                s2 += __shfl_xor(s2, m, 64);
            if (fr == 0) {
                int row = rh * 32 + af * 16 + q4 + r;
                ms[row][ch][0] = vmax;
                ms[row][ch][1] = s2;
            }
        }
    }
    __syncthreads();

    // merge col-halves + lse + block-sum: wave 0, one lane per row
    if (tid < 64) {
        float m0 = ms[tid][0][0], s0 = ms[tid][0][1];
        float m1 = ms[tid][1][0], s1 = ms[tid][1][1];
        float mm = fmaxf(m0, m1);
        float ss = s0 * exp2f((m0 - mm) * INV_TAU_LN2)
                 + s1 * exp2f((m1 - mm) * INV_TAU_LN2);
        float lse = mm + TAU_LN2 * log2f(ss);
        #pragma unroll
        for (int d = 1; d < 64; d <<= 1) lse += __shfl_xor(lse, d, 64);
        if (tid == 0)
            atomicAdd(&out[bi * 32 + bj], lse * (1.0f / Na));
    }
}

extern "C" void kernel_launch(void* const* d_in, const int* in_sizes, int n_in,
                              void* d_out, int out_size, void* d_ws, size_t ws_size,
                              hipStream_t stream) {
    const float* audio  = (const float*)d_in[0];
    const float* visual = (const float*)d_in[1];
    float* out = (float*)d_out;

    unsigned short* asw = (unsigned short*)d_ws;                 // 12.58 MB swizzled A
    unsigned short* bsw = asw + (size_t)AUNITS * 8;              // +6.29 MB swizzled B

    convert_swizzle_kernel<<<dim3(1024), dim3(256), 0, stream>>>(audio, visual, asw, bsw, out);
    gemm_lse_kernel<<<dim3(B_ * B_ * NCH), dim3(256), 0, stream>>>(asw, bsw, out);
}